// Round 1
// baseline (17030.820 us; speedup 1.0000x reference)
//
#include <hip/hip_runtime.h>
#include <hip/hip_bf16.h>

#define BB 512
#define TT 128
#define DD 128
#define HH 128
#define EPSV 1e-6f

// ---------------- ws layout (bytes) ----------------
// [0, 512)                         : invden[128] f32
// [512, 512+16777216)              : gammaH bf16 [B*T][128]
// [.. +16777216)                   : beta   bf16 [B*T][128]
// [.. +458752)                     : packed bf16 weights: Whr(16384), Wfr(16384), Wk(131072), Wr(65536)
// total ~34.0 MB

// ---------------- denom per timestep ----------------
__global__ __launch_bounds__(256) void k_denom(const float* __restrict__ masks,
                                               float* __restrict__ invden) {
    int t = blockIdx.x;
    float s = 0.f;
    for (int idx = threadIdx.x; idx < BB * DD; idx += 256) {
        int b = idx >> 7, j = idx & 127;
        s += masks[((size_t)b * TT + t) * DD + j];
    }
    __shared__ float red[256];
    red[threadIdx.x] = s;
    __syncthreads();
    for (int off = 128; off > 0; off >>= 1) {
        if (threadIdx.x < off) red[threadIdx.x] += red[threadIdx.x + off];
        __syncthreads();
    }
    if (threadIdx.x == 0) invden[t] = 1.f / (red[0] + EPSV);
}

// ---------------- pack recurrent weights to bf16 ----------------
__global__ __launch_bounds__(256) void k_pack(const float* __restrict__ Whr,
                                              const float* __restrict__ Wfr,
                                              const float* __restrict__ Wk,
                                              const float* __restrict__ Wr,
                                              __hip_bfloat16* __restrict__ wp) {
    int i = blockIdx.x * 256 + threadIdx.x;   // grid covers 229376 exactly
    if (i < 16384)       wp[i] = __float2bfloat16(Whr[i]);
    else if (i < 32768)  wp[i] = __float2bfloat16(Wfr[i - 16384]);
    else if (i < 163840) wp[i] = __float2bfloat16(Wk[i - 32768]);
    else                 wp[i] = __float2bfloat16(Wr[i - 163840]);
}

// ---------------- precompute gammaH, beta for all (b,t) ----------------
// block: 256 threads, 32 rows of [B*T, 128]
__global__ __launch_bounds__(256) void k_pre(
    const float* __restrict__ masks, const float* __restrict__ deltas,
    const float* __restrict__ Wth, const float* __restrict__ bth,
    const float* __restrict__ Wtx, const float* __restrict__ btx,
    const float* __restrict__ Wwc, const float* __restrict__ bwc,
    __hip_bfloat16* __restrict__ gH, __hip_bfloat16* __restrict__ beta) {

    __shared__ __align__(16) float dT[32][128];   // reused as bpartS in stage 2
    __shared__ __align__(16) float mT[32][128];
    __shared__ __align__(16) float gx[32][128];

    const int tid = threadIdx.x;
    const int r0 = blockIdx.x * 32;

    {   // load 32 rows of deltas / masks
        const float4* d4 = (const float4*)(deltas + (size_t)r0 * 128);
        const float4* m4 = (const float4*)(masks + (size_t)r0 * 128);
        float4* dT4 = (float4*)&dT[0][0];
        float4* mT4 = (float4*)&mT[0][0];
        for (int i = tid; i < 32 * 32; i += 256) { dT4[i] = d4[i]; mT4[i] = m4[i]; }
    }
    __syncthreads();

    // stage 1: gammaH (cols 0..127) and gamma_x (cols 128..255)
    {
        const int c = tid;
        const float* Wrow = (c < 128) ? (Wth + (size_t)c * DD) : (Wtx + (size_t)(c - 128) * DD);
        const float bias = (c < 128) ? bth[c] : btx[c - 128];
        float acc[32];
#pragma unroll
        for (int r = 0; r < 32; ++r) acc[r] = 0.f;
        for (int k0 = 0; k0 < 128; k0 += 4) {
            float4 w = *(const float4*)(Wrow + k0);
#pragma unroll
            for (int r = 0; r < 32; ++r) {
                float4 a = *(const float4*)&dT[r][k0];
                acc[r] = fmaf(a.x, w.x, fmaf(a.y, w.y, fmaf(a.z, w.z, fmaf(a.w, w.w, acc[r]))));
            }
        }
#pragma unroll
        for (int r = 0; r < 32; ++r) {
            float v = __expf(-fmaxf(acc[r] + bias, 0.f));
            if (c < 128) gH[(size_t)(r0 + r) * 128 + c] = __float2bfloat16(v);
            else         gx[r][c - 128] = v;
        }
    }
    __syncthreads();

    // stage 2: beta = [gamma_x, m] @ Wwc + bwc, split-K across thread halves
    {
        const int c = tid & 127, kh = tid >> 7;
        float acc[32];
#pragma unroll
        for (int r = 0; r < 32; ++r) acc[r] = 0.f;
        const float (*A2)[128] = (kh == 0) ? (const float (*)[128])gx : (const float (*)[128])mT;
        const float* wc = Wwc + (size_t)(kh * 128) * DD + c;
        for (int kk = 0; kk < 128; kk += 4) {
            float w0 = wc[(kk + 0) * DD], w1 = wc[(kk + 1) * DD];
            float w2 = wc[(kk + 2) * DD], w3 = wc[(kk + 3) * DD];
#pragma unroll
            for (int r = 0; r < 32; ++r) {
                float4 a = *(const float4*)&A2[r][kk];
                acc[r] = fmaf(a.x, w0, fmaf(a.y, w1, fmaf(a.z, w2, fmaf(a.w, w3, acc[r]))));
            }
        }
        float (*bpartS)[128] = dT;  // dT is dead after stage 1
        if (kh == 1) {
#pragma unroll
            for (int r = 0; r < 32; ++r) bpartS[r][c] = acc[r];
        }
        __syncthreads();
        if (kh == 0) {
            const float bb = bwc[c];
#pragma unroll
            for (int r = 0; r < 32; ++r) {
                float v = acc[r] + bpartS[r][c] + bb;
                beta[(size_t)(r0 + r) * 128 + c] = __float2bfloat16(v);
            }
        }
    }
}

// ---------------- recurrent kernel: 256 blocks x 2 rows x 512 threads ----------------
__global__ __launch_bounds__(512) void k_rnn(
    const float* __restrict__ values, const float* __restrict__ masks,
    const float* __restrict__ bhr, const float* __restrict__ bfr,
    const float* __restrict__ bl,
    const float* __restrict__ Wd, const float* __restrict__ bd,
    const float* __restrict__ Wo, const float* __restrict__ bo,
    const float* __restrict__ invden,
    const __hip_bfloat16* __restrict__ gHws, const __hip_bfloat16* __restrict__ betws,
    const __hip_bfloat16* __restrict__ wp,
    float* __restrict__ out) {

    const int b0 = blockIdx.x * 2;
    const int tid = threadIdx.x;
    const int lane = tid & 63;
    const int wv = tid >> 6;

    const __hip_bfloat16* Whr_b = wp;
    const __hip_bfloat16* Wfr_b = wp + 16384;
    const __hip_bfloat16* Wk_b  = wp + 32768;    // [256][512]
    const __hip_bfloat16* Wr_b  = wp + 163840;   // [128][512]

    __shared__ __align__(16) float h[2][128];
    __shared__ __align__(16) float cst[2][128];
    __shared__ __align__(16) float xv[2][128];
    __shared__ __align__(16) float mv[2][128];
    __shared__ __align__(16) float bet[2][128];
    __shared__ __align__(16) float xh[2][128];
    __shared__ __align__(16) float xcc[2][128];
    __shared__ float part[4][2][128];
    __shared__ float gp[2][2][512];
    __shared__ float gts[2][512];
    __shared__ float slots[4];
    __shared__ float lossAcc[2];

    for (int i = tid; i < 2 * 128; i += 512) { h[i >> 7][i & 127] = 0.f; cst[i >> 7][i & 127] = 0.f; }
    if (tid < 2) lossAcc[tid] = 0.f;
    __syncthreads();

    for (int t = 0; t < TT; ++t) {
        const float invd = invden[t];

        // ---- load x, m, beta; decay h ----
        if (tid < 256) {
            int row = tid >> 7, j = tid & 127;
            size_t ridx = ((size_t)(b0 + row) * TT + t) * DD + j;
            xv[row][j] = values[ridx];
            mv[row][j] = masks[ridx];
            bet[row][j] = __bfloat162float(betws[ridx]);
            h[row][j] *= __bfloat162float(gHws[ridx]);
        }
        __syncthreads();

        // ---- x_hat partials: thread (j, kq) ----
        {
            const int j = tid & 127, kq = tid >> 7;   // kq in 0..3
            const int kbase = kq * 32;
            float a0 = 0.f, a1 = 0.f;
#pragma unroll 8
            for (int kk = 0; kk < 32; ++kk) {
                float w = __bfloat162float(Whr_b[(size_t)(kbase + kk) * DD + j]);
                a0 = fmaf(h[0][kbase + kk], w, a0);
                a1 = fmaf(h[1][kbase + kk], w, a1);
            }
            part[kq][0][j] = a0; part[kq][1][j] = a1;
        }
        __syncthreads();

        // ---- pw1: reduce x_hat, loss1, x_c ----
        if (tid < 256) {
            int row = tid >> 7, j = tid & 127;
            float xhat = part[0][row][j] + part[1][row][j] + part[2][row][j] + part[3][row][j] + bhr[j];
            xh[row][j] = xhat;
            float xx = xv[row][j], mm = mv[row][j];
            float l = fabsf(xx - xhat) * mm;
            xcc[row][j] = mm * xx + (1.f - mm) * xhat;
            float v = l;
#pragma unroll
            for (int off = 32; off; off >>= 1) v += __shfl_xor(v, off);
            if (lane == 0) slots[wv] = v;
        }
        __syncthreads();
        if (tid < 2) lossAcc[tid] += (slots[2 * tid] + slots[2 * tid + 1]) * invd;

        // ---- z_hat partials (z_hat = x_c @ Wfr^T) ----
        {
            const int j = tid & 127, kq = tid >> 7;
            const int kbase = kq * 32;
            const __hip_bfloat16* wr = Wfr_b + (size_t)j * DD + kbase;
            float a0 = 0.f, a1 = 0.f;
#pragma unroll 8
            for (int kk = 0; kk < 32; ++kk) {
                float w = __bfloat162float(wr[kk]);
                a0 = fmaf(xcc[0][kbase + kk], w, a0);
                a1 = fmaf(xcc[1][kbase + kk], w, a1);
            }
            part[kq][0][j] = a0; part[kq][1][j] = a1;
        }
        __syncthreads();

        // ---- pw2: reduce z_hat, c_hat, loss2+3, c_c (imputation) ----
        if (tid < 256) {
            int row = tid >> 7, j = tid & 127;
            float zhat = part[0][row][j] + part[1][row][j] + part[2][row][j] + part[3][row][j] + bfr[j];
            float bv = bet[row][j];
            float xhat = xh[row][j];
            float chat = bv * zhat + (1.f - bv) * xhat;
            float xx = xv[row][j], mm = mv[row][j];
            float l = (fabsf(xx - zhat) + fabsf(xx - chat)) * mm;
            float cc = mm * xx + (1.f - mm) * chat;
            xcc[row][j] = cc;   // c_c for gates (x_c no longer needed)
            out[512 + ((size_t)(b0 + row) * TT + t) * DD + j] = cc;
            float v = l;
#pragma unroll
            for (int off = 32; off; off >>= 1) v += __shfl_xor(v, off);
            if (lane == 0) slots[wv] = v;
        }
        __syncthreads();
        if (tid < 2) lossAcc[tid] += (slots[2 * tid] + slots[2 * tid + 1]) * invd;

        // ---- gates partials: thread (p = n mod 256, kh = K-half) ----
        {
            const int p = tid & 255, kh = tid >> 8;   // wave-uniform kh
            float a00 = 0.f, a01 = 0.f, a10 = 0.f, a11 = 0.f;

            auto dotseg = [&](const float* A0, const float* A1, const __hip_bfloat16* W, int kn) {
                for (int k = 0; k < kn; k += 4) {
                    float4 av0 = *(const float4*)(A0 + k);
                    float4 av1 = *(const float4*)(A1 + k);
                    const __hip_bfloat16* wb = W + (size_t)k * 512 + p;
                    float w00 = __bfloat162float(wb[0]),    w10 = __bfloat162float(wb[256]);
                    float w01 = __bfloat162float(wb[512]),  w11 = __bfloat162float(wb[768]);
                    float w02 = __bfloat162float(wb[1024]), w12 = __bfloat162float(wb[1280]);
                    float w03 = __bfloat162float(wb[1536]), w13 = __bfloat162float(wb[1792]);
                    a00 = fmaf(av0.x, w00, fmaf(av0.y, w01, fmaf(av0.z, w02, fmaf(av0.w, w03, a00))));
                    a01 = fmaf(av1.x, w00, fmaf(av1.y, w01, fmaf(av1.z, w02, fmaf(av1.w, w03, a01))));
                    a10 = fmaf(av0.x, w10, fmaf(av0.y, w11, fmaf(av0.z, w12, fmaf(av0.w, w13, a10))));
                    a11 = fmaf(av1.x, w10, fmaf(av1.y, w11, fmaf(av1.z, w12, fmaf(av1.w, w13, a11))));
                }
            };
            if (kh == 0) {
                dotseg(&xcc[0][0], &xcc[1][0], Wk_b, 128);                 // c_c @ Wk[0:128]
                dotseg(&mv[0][0],  &mv[1][0],  Wk_b + 128 * 512, 64);      // m[0:64] @ Wk[128:192]
            } else {
                dotseg(&mv[0][64], &mv[1][64], Wk_b + 192 * 512, 64);      // m[64:128] @ Wk[192:256]
                dotseg(&h[0][0],   &h[1][0],   Wr_b, 128);                 // h @ Wr
            }
            gp[kh][0][p]       = a00; gp[kh][1][p]       = a01;
            gp[kh][0][p + 256] = a10; gp[kh][1][p + 256] = a11;
        }
        __syncthreads();

        // ---- gates reduce ----
        for (int pass = 0; pass < 2; ++pass) {
            int idx = pass * 512 + tid;
            int row = idx >> 9, n = idx & 511;
            gts[row][n] = gp[0][row][n] + gp[1][row][n] + bl[n];
        }
        __syncthreads();

        // ---- LSTM update ----
        if (tid < 256) {
            int row = tid >> 7, hj = tid & 127;
            float gi = gts[row][hj], gf = gts[row][128 + hj];
            float gg = gts[row][256 + hj], go = gts[row][384 + hj];
            float si = 1.f / (1.f + __expf(-gi));
            float sf = 1.f / (1.f + __expf(-gf));
            float so = 1.f / (1.f + __expf(-go));
            float tg = tanhf(gg);
            float cn = sf * cst[row][hj] + si * tg;
            float hn = so * tanhf(cn);
            cst[row][hj] = cn;
            h[row][hj] = hn;
        }
        __syncthreads();
    }

    // ---- predictions + custom_loss ----
    if (tid < 256) {
        int row = tid >> 7, j = tid & 127;
        float acc = 0.f;
        for (int k = 0; k < 128; ++k) acc = fmaf(h[row][k], Wd[(size_t)k * DD + j], acc);
        float y = fmaxf(acc + bd[j], 0.f) * Wo[j];
        float v = y;
#pragma unroll
        for (int off = 32; off; off >>= 1) v += __shfl_xor(v, off);
        if (lane == 0) slots[wv] = v;
    }
    __syncthreads();
    if (tid < 2) {
        out[b0 + tid] = slots[2 * tid] + slots[2 * tid + 1] + bo[0];
        out[512 + (size_t)BB * TT * DD + b0 + tid] = lossAcc[tid] * (1.f / TT);
    }
}

extern "C" void kernel_launch(void* const* d_in, const int* in_sizes, int n_in,
                              void* d_out, int out_size, void* d_ws, size_t ws_size,
                              hipStream_t stream) {
    const float* values = (const float*)d_in[0];
    const float* masks  = (const float*)d_in[1];
    const float* deltas = (const float*)d_in[2];
    const float* Wth = (const float*)d_in[3];
    const float* bth = (const float*)d_in[4];
    const float* Wtx = (const float*)d_in[5];
    const float* btx = (const float*)d_in[6];
    const float* Whr = (const float*)d_in[7];
    const float* bhr = (const float*)d_in[8];
    const float* Wfr = (const float*)d_in[9];
    const float* bfr = (const float*)d_in[10];
    const float* Wwc = (const float*)d_in[11];
    const float* bwc = (const float*)d_in[12];
    const float* Wk  = (const float*)d_in[13];
    const float* Wr  = (const float*)d_in[14];
    const float* bl  = (const float*)d_in[15];
    const float* Wd  = (const float*)d_in[16];
    const float* bd  = (const float*)d_in[17];
    const float* Wo  = (const float*)d_in[18];
    const float* bo  = (const float*)d_in[19];
    float* out = (float*)d_out;

    char* ws = (char*)d_ws;
    float* invden = (float*)ws;                                            // 512 B
    __hip_bfloat16* gH    = (__hip_bfloat16*)(ws + 512);                   // 16 MiB
    __hip_bfloat16* beta  = (__hip_bfloat16*)(ws + 512 + 16777216);        // 16 MiB
    __hip_bfloat16* wpack = (__hip_bfloat16*)(ws + 512 + 2 * 16777216);    // 448 KiB

    k_denom<<<TT, 256, 0, stream>>>(masks, invden);
    k_pack<<<896, 256, 0, stream>>>(Whr, Wfr, Wk, Wr, wpack);
    k_pre<<<(BB * TT) / 32, 256, 0, stream>>>(masks, deltas, Wth, bth, Wtx, btx, Wwc, bwc, gH, beta);
    k_rnn<<<BB / 2, 512, 0, stream>>>(values, masks, bhr, bfr, bl, Wd, bd, Wo, bo,
                                      invden, gH, beta, wpack, out);
}

// Round 4
// 991.789 us; speedup vs baseline: 17.1718x; 17.1718x over previous
//
#include <hip/hip_runtime.h>
#include <hip/hip_bf16.h>

#define BB 512
#define TT 128
#define DD 128
#define HH 128
#define EPSV 1e-6f

typedef _Float16 f16x2 __attribute__((ext_vector_type(2)));

__device__ __forceinline__ float dot2f(unsigned a, unsigned b, float c) {
#if __has_builtin(__builtin_amdgcn_fdot2)
    return __builtin_amdgcn_fdot2(__builtin_bit_cast(f16x2, a),
                                  __builtin_bit_cast(f16x2, b), c, false);
#else
    f16x2 fa = __builtin_bit_cast(f16x2, a);
    f16x2 fb = __builtin_bit_cast(f16x2, b);
    return fmaf((float)fa.y, (float)fb.y, fmaf((float)fa.x, (float)fb.x, c));
#endif
}

__device__ __forceinline__ unsigned pkh(float a, float b) {
    f16x2 v; v.x = (_Float16)a; v.y = (_Float16)b;
    return __builtin_bit_cast(unsigned, v);
}

__device__ __forceinline__ float2 uph(unsigned u) {
    f16x2 v = __builtin_bit_cast(f16x2, u);
    return make_float2((float)v.x, (float)v.y);
}

__device__ __forceinline__ float bflo(unsigned u) { return __builtin_bit_cast(float, u << 16); }
__device__ __forceinline__ float bfhi(unsigned u) { return __builtin_bit_cast(float, u & 0xffff0000u); }

__device__ __forceinline__ float sigm(float x) { return 1.f / (1.f + __expf(-x)); }
__device__ __forceinline__ float tanhfast(float x) {
    float t = __expf(2.f * x);
    return 1.f - 2.f / (t + 1.f);
}

// ---------------- denom per timestep ----------------
__global__ __launch_bounds__(256) void k_denom(const float* __restrict__ masks,
                                               float* __restrict__ invden) {
    int t = blockIdx.x;
    float s = 0.f;
    for (int idx = threadIdx.x; idx < BB * DD; idx += 256) {
        int b = idx >> 7, j = idx & 127;
        s += masks[((size_t)b * TT + t) * DD + j];
    }
    __shared__ float red[256];
    red[threadIdx.x] = s;
    __syncthreads();
    for (int off = 128; off > 0; off >>= 1) {
        if (threadIdx.x < off) red[threadIdx.x] += red[threadIdx.x + off];
        __syncthreads();
    }
    if (threadIdx.x == 0) invden[t] = 1.f / (red[0] + EPSV);
}

// ---------------- pack gates weights fp16, per-thread register order ----------------
// W3[k][n]: k<128 -> Wk[k][n] (c_c part); k<256 -> Wr[k-128][n] (h part);
//           k<384 -> Wk[k-128][n] (m part).  Thread t=(kq*64+n8) owns
// k in [kq*48, kq*48+48), n in [n8*8, n8*8+8); reg u32 i = kk2*8+jn holds
// pair (W3[kq*48+2*kk2][n8*8+jn], W3[...+1][...]). Stored so that the 48
// uint4 chunk loads (chunk c at u32 (c*512+t)*4) are lane-coalesced.
__global__ __launch_bounds__(256) void k_pack2(const float* __restrict__ Wk,
                                               const float* __restrict__ Wr,
                                               unsigned* __restrict__ wp2) {
    int idx = blockIdx.x * 256 + threadIdx.x;   // 98304 total
    int c = idx >> 11;
    int t = (idx >> 2) & 511;
    int e = idx & 3;
    int i = c * 4 + e;
    int kq = t >> 6, n8 = t & 63;
    int kk2 = i >> 3, jn = i & 7;
    int k0 = kq * 48 + 2 * kk2;
    int n = n8 * 8 + jn;
    float w0, w1;
    {
        int k = k0;
        w0 = (k < 128) ? Wk[(size_t)k * 512 + n]
           : (k < 256) ? Wr[(size_t)(k - 128) * 512 + n]
                       : Wk[(size_t)(k - 128) * 512 + n];
        k = k0 + 1;
        w1 = (k < 128) ? Wk[(size_t)k * 512 + n]
           : (k < 256) ? Wr[(size_t)(k - 128) * 512 + n]
                       : Wk[(size_t)(k - 128) * 512 + n];
    }
    wp2[idx] = pkh(w0, w1);
}

// ---------------- precompute gammaH, beta for all (b,t) ----------------
__global__ __launch_bounds__(256) void k_pre(
    const float* __restrict__ masks, const float* __restrict__ deltas,
    const float* __restrict__ Wth, const float* __restrict__ bth,
    const float* __restrict__ Wtx, const float* __restrict__ btx,
    const float* __restrict__ Wwc, const float* __restrict__ bwc,
    __hip_bfloat16* __restrict__ gH, __hip_bfloat16* __restrict__ beta) {

    __shared__ __align__(16) float dT[32][128];   // reused as bpartS in stage 2
    __shared__ __align__(16) float mT[32][128];
    __shared__ __align__(16) float gx[32][128];

    const int tid = threadIdx.x;
    const int r0 = blockIdx.x * 32;

    {
        const float4* d4 = (const float4*)(deltas + (size_t)r0 * 128);
        const float4* m4 = (const float4*)(masks + (size_t)r0 * 128);
        float4* dT4 = (float4*)&dT[0][0];
        float4* mT4 = (float4*)&mT[0][0];
        for (int i = tid; i < 32 * 32; i += 256) { dT4[i] = d4[i]; mT4[i] = m4[i]; }
    }
    __syncthreads();

    {
        const int c = tid;
        const float* Wrow = (c < 128) ? (Wth + (size_t)c * DD) : (Wtx + (size_t)(c - 128) * DD);
        const float bias = (c < 128) ? bth[c] : btx[c - 128];
        float acc[32];
#pragma unroll
        for (int r = 0; r < 32; ++r) acc[r] = 0.f;
        for (int k0 = 0; k0 < 128; k0 += 4) {
            float4 w = *(const float4*)(Wrow + k0);
#pragma unroll
            for (int r = 0; r < 32; ++r) {
                float4 a = *(const float4*)&dT[r][k0];
                acc[r] = fmaf(a.x, w.x, fmaf(a.y, w.y, fmaf(a.z, w.z, fmaf(a.w, w.w, acc[r]))));
            }
        }
#pragma unroll
        for (int r = 0; r < 32; ++r) {
            float v = __expf(-fmaxf(acc[r] + bias, 0.f));
            if (c < 128) gH[(size_t)(r0 + r) * 128 + c] = __float2bfloat16(v);
            else         gx[r][c - 128] = v;
        }
    }
    __syncthreads();

    {
        const int c = tid & 127, kh = tid >> 7;
        float acc[32];
#pragma unroll
        for (int r = 0; r < 32; ++r) acc[r] = 0.f;
        const float (*A2)[128] = (kh == 0) ? (const float (*)[128])gx : (const float (*)[128])mT;
        const float* wc = Wwc + (size_t)(kh * 128) * DD + c;
        for (int kk = 0; kk < 128; kk += 4) {
            float w0 = wc[(kk + 0) * DD], w1 = wc[(kk + 1) * DD];
            float w2 = wc[(kk + 2) * DD], w3 = wc[(kk + 3) * DD];
#pragma unroll
            for (int r = 0; r < 32; ++r) {
                float4 a = *(const float4*)&A2[r][kk];
                acc[r] = fmaf(a.x, w0, fmaf(a.y, w1, fmaf(a.z, w2, fmaf(a.w, w3, acc[r]))));
            }
        }
        float (*bpartS)[128] = dT;
        if (kh == 1) {
#pragma unroll
            for (int r = 0; r < 32; ++r) bpartS[r][c] = acc[r];
        }
        __syncthreads();
        if (kh == 0) {
            const float bb = bwc[c];
#pragma unroll
            for (int r = 0; r < 32; ++r) {
                float v = acc[r] + bpartS[r][c] + bb;
                beta[(size_t)(r0 + r) * 128 + c] = __float2bfloat16(v);
            }
        }
    }
}

// ---------------- recurrent kernel: 256 blocks x 2 rows x 512 threads ----------------
__global__ __launch_bounds__(512, 2) void k_rnn2(
    const float* __restrict__ values, const float* __restrict__ masks,
    const float* __restrict__ Whr, const float* __restrict__ bhr,
    const float* __restrict__ Wfr, const float* __restrict__ bfr,
    const float* __restrict__ bl,
    const float* __restrict__ Wd, const float* __restrict__ bd,
    const float* __restrict__ Wo, const float* __restrict__ bo,
    const float* __restrict__ invden,
    const __hip_bfloat16* __restrict__ gHws, const __hip_bfloat16* __restrict__ betws,
    const unsigned* __restrict__ wp2,
    float* __restrict__ out)
{
    const int tid = threadIdx.x;
    const int b0 = blockIdx.x * 2;

    __shared__ __align__(16) unsigned whr2[128][68];  // pad 68: <=8-way, keeps b128 align
    __shared__ __align__(16) unsigned wfr2[128][68];
    __shared__ __align__(16) unsigned ag2[2][192];    // [0..63]=c_c pairs, [64..127]=h pairs, [128..191]=m pairs
    __shared__ __align__(16) unsigned xc2[2][64];
    __shared__ __align__(16) float part[4][2][128];
    __shared__ __align__(16) float gp[8][2][512];
    __shared__ __align__(16) float cst[2][128];
    __shared__ float blS[512];
    __shared__ float invdS[128];
    __shared__ float bhrS[128], bfrS[128];
    __shared__ float slots[8];
    __shared__ float lossAcc[2];

    // ---- gates weights into registers (192 u32 of fp16 pairs) ----
    unsigned wr_[192];
    {
        const uint4* wp4 = (const uint4*)wp2;
#pragma unroll
        for (int c = 0; c < 48; ++c) {
            uint4 q = wp4[c * 512 + tid];
            wr_[c * 4 + 0] = q.x; wr_[c * 4 + 1] = q.y;
            wr_[c * 4 + 2] = q.z; wr_[c * 4 + 3] = q.w;
        }
    }
    // ---- stage Whr / Wfr as fp16 k-pairs in LDS ----
    for (int idx = tid; idx < 8192; idx += 512) {
        int k2 = idx >> 7, j = idx & 127;
        whr2[j][k2] = pkh(Whr[(size_t)(2 * k2) * DD + j], Whr[(size_t)(2 * k2 + 1) * DD + j]);
    }
    for (int idx = tid; idx < 8192; idx += 512) {
        int j = idx >> 6, k2 = idx & 63;
        float2 w = *(const float2*)&Wfr[(size_t)j * DD + 2 * k2];
        wfr2[j][k2] = pkh(w.x, w.y);
    }
    blS[tid] = bl[tid];
    if (tid < 128) { invdS[tid] = invden[tid]; bhrS[tid] = bhr[tid]; bfrS[tid] = bfr[tid]; }
    if (tid < 128) {
        int row = tid >> 6, j2 = tid & 63;
        ag2[row][64 + j2] = 0u;                     // h = 0
        *(float2*)&cst[row][2 * j2] = make_float2(0.f, 0.f);
    }
    if (tid < 2) lossAcc[tid] = 0.f;

    const int prow = tid >> 6, pj2 = tid & 63;      // pw-thread coords (valid for tid<128)
    const int pj = tid & 127, pkq4 = tid >> 7;      // GEMV coords (kq 0..3)
    const int gkq = tid >> 6, gn8 = tid & 63;       // gates coords (kq 0..7)

    // prefetch t=0 streaming operands
    float2 px, pm;
    unsigned pbet = 0, pgh = 0;
    if (tid < 128) {
        size_t r2 = ((size_t)(b0 + prow) * TT + 0) * DD + 2 * pj2;
        px = *(const float2*)(values + r2);
        pm = *(const float2*)(masks + r2);
        pbet = *(const unsigned*)(betws + r2);
        pgh  = *(const unsigned*)(gHws + r2);
    }
    __syncthreads();

    float xhat0 = 0.f, xhat1 = 0.f;
    float cx0 = 0.f, cx1 = 0.f, cm0 = 0.f, cm1 = 0.f;
    unsigned cbet = 0;

    for (int t = 0; t < TT; ++t) {
        // ---- ph0: consume prefetch, decay h, publish m pairs ----
        if (tid < 128) {
            cx0 = px.x; cx1 = px.y; cm0 = pm.x; cm1 = pm.y; cbet = pbet;
            float g0 = bflo(pgh), g1 = bfhi(pgh);
            float2 hv = uph(ag2[prow][64 + pj2]);
            ag2[prow][64 + pj2] = pkh(hv.x * g0, hv.y * g1);
            ag2[prow][128 + pj2] = pkh(cm0, cm1);
        }
        __syncthreads();

        // ---- ph1: x_hat partials (h @ Whr), dot2 over fp16 pairs ----
        {
            const unsigned* wrow = &whr2[pj][pkq4 * 16];
            uint4 w0 = *(const uint4*)(wrow + 0);
            uint4 w1 = *(const uint4*)(wrow + 4);
            uint4 w2 = *(const uint4*)(wrow + 8);
            uint4 w3 = *(const uint4*)(wrow + 12);
            float s0 = 0.f, s1 = 0.f;
#pragma unroll
            for (int row = 0; row < 2; ++row) {
                const unsigned* ha = &ag2[row][64 + pkq4 * 16];
                uint4 a0 = *(const uint4*)(ha + 0);
                uint4 a1 = *(const uint4*)(ha + 4);
                uint4 a2 = *(const uint4*)(ha + 8);
                uint4 a3 = *(const uint4*)(ha + 12);
                float s = 0.f;
                s = dot2f(a0.x, w0.x, s); s = dot2f(a0.y, w0.y, s);
                s = dot2f(a0.z, w0.z, s); s = dot2f(a0.w, w0.w, s);
                s = dot2f(a1.x, w1.x, s); s = dot2f(a1.y, w1.y, s);
                s = dot2f(a1.z, w1.z, s); s = dot2f(a1.w, w1.w, s);
                s = dot2f(a2.x, w2.x, s); s = dot2f(a2.y, w2.y, s);
                s = dot2f(a2.z, w2.z, s); s = dot2f(a2.w, w2.w, s);
                s = dot2f(a3.x, w3.x, s); s = dot2f(a3.y, w3.y, s);
                s = dot2f(a3.z, w3.z, s); s = dot2f(a3.w, w3.w, s);
                if (row == 0) s0 = s; else s1 = s;
            }
            part[pkq4][0][pj] = s0;
            part[pkq4][1][pj] = s1;
        }
        __syncthreads();

        // ---- ph2: x_hat reduce, loss1, x_c ----
        if (tid < 128) {
            float2 p0 = *(const float2*)&part[0][prow][2 * pj2];
            float2 p1 = *(const float2*)&part[1][prow][2 * pj2];
            float2 p2 = *(const float2*)&part[2][prow][2 * pj2];
            float2 p3 = *(const float2*)&part[3][prow][2 * pj2];
            xhat0 = p0.x + p1.x + p2.x + p3.x + bhrS[2 * pj2];
            xhat1 = p0.y + p1.y + p2.y + p3.y + bhrS[2 * pj2 + 1];
            float xc0 = cm0 * cx0 + (1.f - cm0) * xhat0;
            float xc1 = cm1 * cx1 + (1.f - cm1) * xhat1;
            xc2[prow][pj2] = pkh(xc0, xc1);
            float l = fabsf(cx0 - xhat0) * cm0 + fabsf(cx1 - xhat1) * cm1;
#pragma unroll
            for (int off = 32; off; off >>= 1) l += __shfl_xor(l, off);
            if ((tid & 63) == 0) slots[prow] = l;
        }
        __syncthreads();

        // ---- ph3: z_hat partials (x_c @ Wfr^T) ----
        {
            const unsigned* wrow = &wfr2[pj][pkq4 * 16];
            uint4 w0 = *(const uint4*)(wrow + 0);
            uint4 w1 = *(const uint4*)(wrow + 4);
            uint4 w2 = *(const uint4*)(wrow + 8);
            uint4 w3 = *(const uint4*)(wrow + 12);
            float s0 = 0.f, s1 = 0.f;
#pragma unroll
            for (int row = 0; row < 2; ++row) {
                const unsigned* xa = &xc2[row][pkq4 * 16];
                uint4 a0 = *(const uint4*)(xa + 0);
                uint4 a1 = *(const uint4*)(xa + 4);
                uint4 a2 = *(const uint4*)(xa + 8);
                uint4 a3 = *(const uint4*)(xa + 12);
                float s = 0.f;
                s = dot2f(a0.x, w0.x, s); s = dot2f(a0.y, w0.y, s);
                s = dot2f(a0.z, w0.z, s); s = dot2f(a0.w, w0.w, s);
                s = dot2f(a1.x, w1.x, s); s = dot2f(a1.y, w1.y, s);
                s = dot2f(a1.z, w1.z, s); s = dot2f(a1.w, w1.w, s);
                s = dot2f(a2.x, w2.x, s); s = dot2f(a2.y, w2.y, s);
                s = dot2f(a2.z, w2.z, s); s = dot2f(a2.w, w2.w, s);
                s = dot2f(a3.x, w3.x, s); s = dot2f(a3.y, w3.y, s);
                s = dot2f(a3.z, w3.z, s); s = dot2f(a3.w, w3.w, s);
                if (row == 0) s0 = s; else s1 = s;
            }
            part[pkq4][0][pj] = s0;
            part[pkq4][1][pj] = s1;
        }
        __syncthreads();

        // ---- ph4: z_hat reduce, c_hat, loss2+3, c_c + imputation store ----
        if (tid < 128) {
            float2 p0 = *(const float2*)&part[0][prow][2 * pj2];
            float2 p1 = *(const float2*)&part[1][prow][2 * pj2];
            float2 p2 = *(const float2*)&part[2][prow][2 * pj2];
            float2 p3 = *(const float2*)&part[3][prow][2 * pj2];
            float z0 = p0.x + p1.x + p2.x + p3.x + bfrS[2 * pj2];
            float z1 = p0.y + p1.y + p2.y + p3.y + bfrS[2 * pj2 + 1];
            float be0 = bflo(cbet), be1 = bfhi(cbet);
            float ch0 = be0 * z0 + (1.f - be0) * xhat0;
            float ch1 = be1 * z1 + (1.f - be1) * xhat1;
            float l = (fabsf(cx0 - z0) + fabsf(cx0 - ch0)) * cm0
                    + (fabsf(cx1 - z1) + fabsf(cx1 - ch1)) * cm1;
            float cc0 = cm0 * cx0 + (1.f - cm0) * ch0;
            float cc1 = cm1 * cx1 + (1.f - cm1) * ch1;
            ag2[prow][pj2] = pkh(cc0, cc1);
            size_t r2 = ((size_t)(b0 + prow) * TT + t) * DD + 2 * pj2;
            *(float2*)&out[512 + r2] = make_float2(cc0, cc1);
#pragma unroll
            for (int off = 32; off; off >>= 1) l += __shfl_xor(l, off);
            if ((tid & 63) == 0) slots[2 + prow] = l;
        }
        __syncthreads();

        // ---- ph5: gates = [c_c; h; m] @ [Wk0; Wr; Wk1] from registers ----
        if (tid < 128) {   // prefetch next step's streaming operands (latency hides under dot2s)
            int tc = (t + 1 < TT) ? t + 1 : TT - 1;
            size_t r2 = ((size_t)(b0 + prow) * TT + tc) * DD + 2 * pj2;
            px = *(const float2*)(values + r2);
            pm = *(const float2*)(masks + r2);
            pbet = *(const unsigned*)(betws + r2);
            pgh  = *(const unsigned*)(gHws + r2);
        }
        {
            float acc0[8], acc1[8];
#pragma unroll
            for (int j = 0; j < 8; ++j) { acc0[j] = 0.f; acc1[j] = 0.f; }
#pragma unroll
            for (int c = 0; c < 6; ++c) {
                uint4 qa = *(const uint4*)&ag2[0][gkq * 24 + c * 4];
                uint4 qb = *(const uint4*)&ag2[1][gkq * 24 + c * 4];
#define GSTEP(AC, BC, E)                                        \
                {                                               \
                    _Pragma("unroll")                           \
                    for (int j = 0; j < 8; ++j) {               \
                        unsigned w = wr_[(c * 4 + (E)) * 8 + j];\
                        acc0[j] = dot2f((AC), w, acc0[j]);      \
                        acc1[j] = dot2f((BC), w, acc1[j]);      \
                    }                                           \
                }
                GSTEP(qa.x, qb.x, 0)
                GSTEP(qa.y, qb.y, 1)
                GSTEP(qa.z, qb.z, 2)
                GSTEP(qa.w, qb.w, 3)
#undef GSTEP
            }
            *(float4*)&gp[gkq][0][gn8 * 8]     = make_float4(acc0[0], acc0[1], acc0[2], acc0[3]);
            *(float4*)&gp[gkq][0][gn8 * 8 + 4] = make_float4(acc0[4], acc0[5], acc0[6], acc0[7]);
            *(float4*)&gp[gkq][1][gn8 * 8]     = make_float4(acc1[0], acc1[1], acc1[2], acc1[3]);
            *(float4*)&gp[gkq][1][gn8 * 8 + 4] = make_float4(acc1[4], acc1[5], acc1[6], acc1[7]);
        }
        __syncthreads();

        // ---- ph6: gates reduce + LSTM update; loss combine ----
        if (tid < 128) {
            float2 gi = make_float2(blS[2 * pj2],       blS[2 * pj2 + 1]);
            float2 gf = make_float2(blS[128 + 2 * pj2], blS[128 + 2 * pj2 + 1]);
            float2 gg = make_float2(blS[256 + 2 * pj2], blS[256 + 2 * pj2 + 1]);
            float2 go = make_float2(blS[384 + 2 * pj2], blS[384 + 2 * pj2 + 1]);
#pragma unroll
            for (int kq = 0; kq < 8; ++kq) {
                float2 v;
                v = *(const float2*)&gp[kq][prow][2 * pj2];       gi.x += v.x; gi.y += v.y;
                v = *(const float2*)&gp[kq][prow][128 + 2 * pj2]; gf.x += v.x; gf.y += v.y;
                v = *(const float2*)&gp[kq][prow][256 + 2 * pj2]; gg.x += v.x; gg.y += v.y;
                v = *(const float2*)&gp[kq][prow][384 + 2 * pj2]; go.x += v.x; go.y += v.y;
            }
            float2 cv = *(const float2*)&cst[prow][2 * pj2];
            float cn0 = sigm(gf.x) * cv.x + sigm(gi.x) * tanhfast(gg.x);
            float cn1 = sigm(gf.y) * cv.y + sigm(gi.y) * tanhfast(gg.y);
            float hn0 = sigm(go.x) * tanhfast(cn0);
            float hn1 = sigm(go.y) * tanhfast(cn1);
            *(float2*)&cst[prow][2 * pj2] = make_float2(cn0, cn1);
            ag2[prow][64 + pj2] = pkh(hn0, hn1);
        }
        if (tid < 2) lossAcc[tid] += (slots[tid] + slots[2 + tid]) * invdS[t];
        __syncthreads();
    }

    // ---- predictions + custom_loss ----
    if (tid < 256) {
        int row = tid >> 7, j = tid & 127;
        float acc = 0.f;
        for (int k2 = 0; k2 < 64; ++k2) {
            float2 hv = uph(ag2[row][64 + k2]);
            acc = fmaf(hv.x, Wd[(size_t)(2 * k2) * DD + j], acc);
            acc = fmaf(hv.y, Wd[(size_t)(2 * k2 + 1) * DD + j], acc);
        }
        float y = fmaxf(acc + bd[j], 0.f) * Wo[j];
#pragma unroll
        for (int off = 32; off; off >>= 1) y += __shfl_xor(y, off);
        if ((tid & 63) == 0) slots[tid >> 6] = y;
    }
    __syncthreads();
    if (tid < 2) {
        out[b0 + tid] = slots[2 * tid] + slots[2 * tid + 1] + bo[0];
        out[512 + (size_t)BB * TT * DD + b0 + tid] = lossAcc[tid] * (1.f / TT);
    }
}

extern "C" void kernel_launch(void* const* d_in, const int* in_sizes, int n_in,
                              void* d_out, int out_size, void* d_ws, size_t ws_size,
                              hipStream_t stream) {
    const float* values = (const float*)d_in[0];
    const float* masks  = (const float*)d_in[1];
    const float* deltas = (const float*)d_in[2];
    const float* Wth = (const float*)d_in[3];
    const float* bth = (const float*)d_in[4];
    const float* Wtx = (const float*)d_in[5];
    const float* btx = (const float*)d_in[6];
    const float* Whr = (const float*)d_in[7];
    const float* bhr = (const float*)d_in[8];
    const float* Wfr = (const float*)d_in[9];
    const float* bfr = (const float*)d_in[10];
    const float* Wwc = (const float*)d_in[11];
    const float* bwc = (const float*)d_in[12];
    const float* Wk  = (const float*)d_in[13];
    const float* Wr  = (const float*)d_in[14];
    const float* bl  = (const float*)d_in[15];
    const float* Wd  = (const float*)d_in[16];
    const float* bd  = (const float*)d_in[17];
    const float* Wo  = (const float*)d_in[18];
    const float* bo  = (const float*)d_in[19];
    float* out = (float*)d_out;

    char* ws = (char*)d_ws;
    float* invden        = (float*)ws;                                  // 512 B
    __hip_bfloat16* gH   = (__hip_bfloat16*)(ws + 512);                 // 16 MiB
    __hip_bfloat16* beta = (__hip_bfloat16*)(ws + 512 + 16777216);      // 16 MiB
    unsigned* wp2        = (unsigned*)(ws + 512 + 2 * 16777216);        // 384 KiB

    k_denom<<<TT, 256, 0, stream>>>(masks, invden);
    k_pack2<<<384, 256, 0, stream>>>(Wk, Wr, wp2);
    k_pre<<<(BB * TT) / 32, 256, 0, stream>>>(masks, deltas, Wth, bth, Wtx, btx, Wwc, bwc, gH, beta);
    k_rnn2<<<BB / 2, 512, 0, stream>>>(values, masks, Whr, bhr, Wfr, bfr, bl,
                                       Wd, bd, Wo, bo, invden, gH, beta, wp2, out);
}